// Round 5
// baseline (837.828 us; speedup 1.0000x reference)
//
#include <hip/hip_runtime.h>

// Problem constants (from reference): T=1024, B=32, D=768, L=48
#define T_ 1024
#define B_ 32
#define D_ 768
#define L_ 48
#define TB_ (T_ * B_)   // 32768 rows of the emissions GEMM

// ---------------------------------------------------------------------------
// Kernel A: E = exp(feats @ W + b)   (fp32, M=32768 N=48 K=768)
// block = 256 threads (4 waves), tile = 128 rows x 48 cols, K-chunks of 64.
// DOUBLE-BUFFERED: feats for chunk k+1 staged via global_load_lds into
// fbuf[nxt] while chunk k computes from fbuf[cur]; W chunk k+1 loaded to
// VGPRs at loop top, stored to wbuf[nxt] after compute. One barrier/chunk.
// XOR swizzle on fbuf + rows-strided-32 microtile -> conflict-free reads.
// ---------------------------------------------------------------------------
__global__ __launch_bounds__(256, 1) void emis_gemm(
    const float* __restrict__ feats, const float* __restrict__ W,
    const float* __restrict__ bias, float* __restrict__ E) {
  __shared__ float fbuf[2][128 * 64];  // row-major, 16 chunks of 16B per row
  __shared__ float wbuf[2][48 * 68];   // wbuf[j][ko], padded
  const int tid = threadIdx.x;
  const int wv = tid >> 6;   // wave id 0..3
  const int lane = tid & 63;
  const int cg = tid & 7;    // col group -> cols c0..c0+5
  const int rg = tid >> 3;   // row group 0..31 -> rows rg+32i
  const int c0 = cg * 6;
  const int rowbase = blockIdx.x * 128;
  const int r7 = rg & 7;

  float acc[4][6];
#pragma unroll
  for (int i = 0; i < 4; i++)
#pragma unroll
    for (int c = 0; c < 6; c++) acc[i][c] = 0.f;

  float wreg[12];

  // async-stage feats chunk kc into fbuf[bufi] (8 global_load_lds per wave)
  auto stage_feats = [&](int kc, int bufi) {
#pragma unroll
    for (int inst = 0; inst < 8; inst++) {
      const int rowstart = wv * 32 + inst * 4;
      const int r = rowstart + (lane >> 4);
      const int slot = lane & 15;
      const int gch = slot ^ (r & 7);
      const float* g = feats + (size_t)(rowbase + r) * D_ + kc + gch * 4;
      float* l = &fbuf[bufi][rowstart * 64];  // wave-uniform base
      __builtin_amdgcn_global_load_lds(
          (const __attribute__((address_space(1))) uint32_t*)g,
          (__attribute__((address_space(3))) uint32_t*)l, 16, 0, 0);
    }
  };
  auto load_w = [&](int kc) {
#pragma unroll
    for (int i = 0; i < 12; i++) {
      const int idx = tid + i * 256;  // 0..3071
      const int ko = idx / 48;
      const int j = idx - ko * 48;
      wreg[i] = W[(kc + ko) * L_ + j];
    }
  };
  auto store_w = [&](int bufi) {
#pragma unroll
    for (int i = 0; i < 12; i++) {
      const int idx = tid + i * 256;
      const int ko = idx / 48;
      const int j = idx - ko * 48;
      wbuf[bufi][j * 68 + ko] = wreg[i];  // transposed: wbuf[j][ko]
    }
  };

  // prologue: chunk 0 into buffer 0
  stage_feats(0, 0);
  load_w(0);
  store_w(0);
  __syncthreads();  // drains feats chunk0 (vmcnt) + W writes (lgkm)

  for (int c = 0; c < 12; c++) {
    const int cur = c & 1, nxt = cur ^ 1;
    if (c + 1 < 12) {
      stage_feats((c + 1) * 64, nxt);  // async; lands during compute
      load_w((c + 1) * 64);            // VGPR loads; land during compute
    }
#pragma unroll 4
    for (int k4 = 0; k4 < 16; k4++) {
      float4 fv[4];
      float4 wv4[6];
      const int sch = (k4 ^ r7) << 2;  // swizzled chunk offset (floats)
#pragma unroll
      for (int i = 0; i < 4; i++)
        fv[i] = *(const float4*)(&fbuf[cur][(rg + 32 * i) * 64 + sch]);
#pragma unroll
      for (int cc = 0; cc < 6; cc++)
        wv4[cc] = *(const float4*)(&wbuf[cur][(c0 + cc) * 68 + k4 * 4]);
#pragma unroll
      for (int i = 0; i < 4; i++) {
#pragma unroll
        for (int cc = 0; cc < 6; cc++) {
          acc[i][cc] = fmaf(fv[i].x, wv4[cc].x, acc[i][cc]);
          acc[i][cc] = fmaf(fv[i].y, wv4[cc].y, acc[i][cc]);
          acc[i][cc] = fmaf(fv[i].z, wv4[cc].z, acc[i][cc]);
          acc[i][cc] = fmaf(fv[i].w, wv4[cc].w, acc[i][cc]);
        }
      }
    }
    if (c + 1 < 12) store_w(nxt);  // W loads landed during compute
    __syncthreads();               // all waves done with [cur]; [nxt] staged
  }

  // epilogue: E = exp(acc + bias), rows rg+32i, cols c0..c0+5 (float2 x3)
#pragma unroll
  for (int i = 0; i < 4; i++) {
    float* dst = E + (size_t)(rowbase + rg + 32 * i) * L_ + c0;
#pragma unroll
    for (int c = 0; c < 6; c += 2) {
      float2 v;
      v.x = __expf(acc[i][c + 0] + bias[c0 + c + 0]);
      v.y = __expf(acc[i][c + 1] + bias[c0 + c + 1]);
      *(float2*)(dst + c) = v;
    }
  }
}

// ---------------------------------------------------------------------------
// Kernel B: CRF forward scans, scaled probability space, readlane matvec.
// PACKING FIX: 8 waves (512 thr) per block, 8 blocks -> 2 waves per SIMD.
// A single wave/SIMD runs at ~5.4 cyc/inst (dependency bubbles, nothing
// co-resident to fill them — R4 evidence); 2 waves/SIMD interleave to issue
// rate (~2 cyc/inst). Each wave handles one (pass,b) sequence; no barriers.
// Tag mask folded into prefetched emission (ev=0), off the critical chain.
// ---------------------------------------------------------------------------
__global__ __launch_bounds__(512, 2) void crf_scan(
    const float* __restrict__ E, const int* __restrict__ tags,
    const int* __restrict__ lens, const float* __restrict__ begin,
    const float* __restrict__ trans, const float* __restrict__ endt,
    const int* __restrict__ bc, const int* __restrict__ ec,
    const int* __restrict__ tc, float* __restrict__ out) {
  const int wvid = threadIdx.x >> 6;
  const int lane = threadIdx.x & 63;
  const int s = blockIdx.x * 8 + wvid;  // 0..63
  const int pass = s & 1;  // 0 = unconstrained fwd, 1 = constrained partial
  const int b = s >> 1;
  const bool act = lane < L_;
  const int len = lens[b];  // in [512, 1024]
  const int stride = B_ * L_;
  const int base = b * L_ + (act ? lane : 0);  // clamped for lanes 48..63

  // Transition row in registers; 0 for inactive lanes and constrained entries
  float P[L_];
#pragma unroll
  for (int k = 0; k < L_; k++) P[k] = 0.f;
  if (act) {
#pragma unroll
    for (int k = 0; k < L_; k++) {
      float p = __expf(trans[lane * L_ + k]);
      if (pass && tc[lane * L_ + k]) p = 0.f;
      P[k] = p;
    }
  }

  // init state: a0 = E[0]*exp(begin), masked for pass 1
  float a = 0.f;
  if (act) {
    a = E[base] * __expf(begin[lane]);
    if (pass && (bc[lane] || tags[base])) a = 0.f;
  }
  float logacc = 0.f;

  // pre-masked emission load: 0 where the tag mask disallows (pass 1 only)
  auto ldE = [&](int tt) -> float {
    float v = E[tt * stride + base];
    if (pass && tags[tt * stride + base]) v = 0.f;
    return v;
  };

  auto step = [&](float ev, bool rescale) {
    // phase 1: broadcast the whole state into uniform regs
    const int ai = __float_as_int(a);
    int sa[L_];
#pragma unroll
    for (int k = 0; k < L_; k++) sa[k] = __builtin_amdgcn_readlane(ai, k);
    // phase 2: matvec, 4 independent chains
    float s0 = 0.f, s1 = 0.f, s2 = 0.f, s3 = 0.f;
#pragma unroll
    for (int k = 0; k < L_; k += 4) {
      s0 = fmaf(__int_as_float(sa[k + 0]), P[k + 0], s0);
      s1 = fmaf(__int_as_float(sa[k + 1]), P[k + 1], s1);
      s2 = fmaf(__int_as_float(sa[k + 2]), P[k + 2], s2);
      s3 = fmaf(__int_as_float(sa[k + 3]), P[k + 3], s3);
    }
    float u = ((s0 + s1) + (s2 + s3)) * ev;
    if (rescale) {
      float m = u;
#pragma unroll
      for (int off = 32; off; off >>= 1) m = fmaxf(m, __shfl_xor(m, off, 64));
      m = fmaxf(m, 1e-30f);
      u = u * __builtin_amdgcn_rcpf(m);  // log(m) compensates; eps ~2^-22
      logacc += __logf(m);
    }
    a = u;
  };

  // preload emissions for t = 1..8 (len >= 512 so always valid)
  float e8[8];
#pragma unroll
  for (int i = 0; i < 8; i++) e8[i] = ldE(1 + i);

  int t = 1;  // t stays == 1 (mod 8); rescale lands at unrolled i == 7
  for (; t + 8 <= len; t += 8) {
    float p8[8];
#pragma unroll
    for (int i = 0; i < 8; i++) {
      int tt = t + 8 + i;
      tt = (tt < len) ? tt : (len - 1);
      p8[i] = ldE(tt);
    }
#pragma unroll
    for (int i = 0; i < 8; i++) step(e8[i], i == 7);
#pragma unroll
    for (int i = 0; i < 8; i++) e8[i] = p8[i];
  }
  // tail: at most 7 steps, e8 already holds times t..t+7 (clamped)
#pragma unroll
  for (int i = 0; i < 8; i++) {
    if (t + i < len) step(e8[i], false);
  }

  // readout: logZ = logacc + log(sum_j a[j]*exp(end[j]))
  float z = 0.f;
  if (act) {
    float ez = __expf(endt[lane]);
    if (pass && ec[lane]) ez = 0.f;
    z = a * ez;
  }
#pragma unroll
  for (int off = 32; off; off >>= 1) z += __shfl_xor(z, off, 64);
  const float logZ = logacc + __logf(z);
  if (lane == 0) atomicAdd(out + b, pass ? -logZ : logZ);
}

// ---------------------------------------------------------------------------
extern "C" void kernel_launch(void* const* d_in, const int* in_sizes, int n_in,
                              void* d_out, int out_size, void* d_ws,
                              size_t ws_size, hipStream_t stream) {
  (void)in_sizes; (void)n_in; (void)out_size; (void)ws_size;
  const float* feats = (const float*)d_in[0];
  const int* tags = (const int*)d_in[1];
  const int* lens = (const int*)d_in[2];
  const float* W = (const float*)d_in[3];
  const float* bias = (const float*)d_in[4];
  const float* begin = (const float*)d_in[5];
  const float* trans = (const float*)d_in[6];
  const float* endt = (const float*)d_in[7];
  const int* bc = (const int*)d_in[8];
  const int* ec = (const int*)d_in[9];
  const int* tc = (const int*)d_in[10];

  float* E = (float*)d_ws;  // T*B*L floats = 6 MB scratch, exp(emissions)
  float* out = (float*)d_out;

  hipMemsetAsync(d_out, 0, B_ * sizeof(float), stream);

  emis_gemm<<<dim3(TB_ / 128), dim3(256), 0, stream>>>(feats, W, bias, E);
  crf_scan<<<dim3(8), dim3(512), 0, stream>>>(E, tags, lens, begin, trans,
                                              endt, bc, ec, tc, out);
}

// Round 6
// 805.760 us; speedup vs baseline: 1.0398x; 1.0398x over previous
//
#include <hip/hip_runtime.h>

// Problem constants (from reference): T=1024, B=32, D=768, L=48
#define T_ 1024
#define B_ 32
#define D_ 768
#define L_ 48
#define TB_ (T_ * B_)   // 32768 rows of the emissions GEMM

// ---------------------------------------------------------------------------
// Kernel A: E = exp(feats @ W + b)  — UNCHANGED from R5 (control variable;
// the non-scan time remainder has been invariant ~202-213 us across three
// different GEMM structures; once the scan drops below it we get counters).
// ---------------------------------------------------------------------------
__global__ __launch_bounds__(256, 1) void emis_gemm(
    const float* __restrict__ feats, const float* __restrict__ W,
    const float* __restrict__ bias, float* __restrict__ E) {
  __shared__ float fbuf[2][128 * 64];  // row-major, 16 chunks of 16B per row
  __shared__ float wbuf[2][48 * 68];   // wbuf[j][ko], padded
  const int tid = threadIdx.x;
  const int wv = tid >> 6;   // wave id 0..3
  const int lane = tid & 63;
  const int cg = tid & 7;    // col group -> cols c0..c0+5
  const int rg = tid >> 3;   // row group 0..31 -> rows rg+32i
  const int c0 = cg * 6;
  const int rowbase = blockIdx.x * 128;
  const int r7 = rg & 7;

  float acc[4][6];
#pragma unroll
  for (int i = 0; i < 4; i++)
#pragma unroll
    for (int c = 0; c < 6; c++) acc[i][c] = 0.f;

  float wreg[12];

  auto stage_feats = [&](int kc, int bufi) {
#pragma unroll
    for (int inst = 0; inst < 8; inst++) {
      const int rowstart = wv * 32 + inst * 4;
      const int r = rowstart + (lane >> 4);
      const int slot = lane & 15;
      const int gch = slot ^ (r & 7);
      const float* g = feats + (size_t)(rowbase + r) * D_ + kc + gch * 4;
      float* l = &fbuf[bufi][rowstart * 64];  // wave-uniform base
      __builtin_amdgcn_global_load_lds(
          (const __attribute__((address_space(1))) uint32_t*)g,
          (__attribute__((address_space(3))) uint32_t*)l, 16, 0, 0);
    }
  };
  auto load_w = [&](int kc) {
#pragma unroll
    for (int i = 0; i < 12; i++) {
      const int idx = tid + i * 256;  // 0..3071
      const int ko = idx / 48;
      const int j = idx - ko * 48;
      wreg[i] = W[(kc + ko) * L_ + j];
    }
  };
  auto store_w = [&](int bufi) {
#pragma unroll
    for (int i = 0; i < 12; i++) {
      const int idx = tid + i * 256;
      const int ko = idx / 48;
      const int j = idx - ko * 48;
      wbuf[bufi][j * 68 + ko] = wreg[i];  // transposed: wbuf[j][ko]
    }
  };

  stage_feats(0, 0);
  load_w(0);
  store_w(0);
  __syncthreads();  // drains feats chunk0 (vmcnt) + W writes (lgkm)

  for (int c = 0; c < 12; c++) {
    const int cur = c & 1, nxt = cur ^ 1;
    if (c + 1 < 12) {
      stage_feats((c + 1) * 64, nxt);  // async; lands during compute
      load_w((c + 1) * 64);            // VGPR loads; land during compute
    }
#pragma unroll 4
    for (int k4 = 0; k4 < 16; k4++) {
      float4 fv[4];
      float4 wv4[6];
      const int sch = (k4 ^ r7) << 2;  // swizzled chunk offset (floats)
#pragma unroll
      for (int i = 0; i < 4; i++)
        fv[i] = *(const float4*)(&fbuf[cur][(rg + 32 * i) * 64 + sch]);
#pragma unroll
      for (int cc = 0; cc < 6; cc++)
        wv4[cc] = *(const float4*)(&wbuf[cur][(c0 + cc) * 68 + k4 * 4]);
#pragma unroll
      for (int i = 0; i < 4; i++) {
#pragma unroll
        for (int cc = 0; cc < 6; cc++) {
          acc[i][cc] = fmaf(fv[i].x, wv4[cc].x, acc[i][cc]);
          acc[i][cc] = fmaf(fv[i].y, wv4[cc].y, acc[i][cc]);
          acc[i][cc] = fmaf(fv[i].z, wv4[cc].z, acc[i][cc]);
          acc[i][cc] = fmaf(fv[i].w, wv4[cc].w, acc[i][cc]);
        }
      }
    }
    if (c + 1 < 12) store_w(nxt);  // W loads landed during compute
    __syncthreads();               // all waves done with [cur]; [nxt] staged
  }

#pragma unroll
  for (int i = 0; i < 4; i++) {
    float* dst = E + (size_t)(rowbase + rg + 32 * i) * L_ + c0;
#pragma unroll
    for (int c = 0; c < 6; c += 2) {
      float2 v;
      v.x = __expf(acc[i][c + 0] + bias[c0 + c + 0]);
      v.y = __expf(acc[i][c + 1] + bias[c0 + c + 1]);
      *(float2*)(dst + c) = v;
    }
  }
}

// ---------------------------------------------------------------------------
// Kernel B: CRF forward scans, scaled probability space.
// Back to best config: 64 blocks x 1 wave (R4: 570 cyc/step).
// R6 fix: the 570 floor is the VALU-writes-SGPR -> VALU-reads-SGPR RAW
// hazard (~7 cyc x 48) from the compiler interleaving readlane/fma pairs.
// Enforce phase separation with sched_barrier(0): ALL 48 v_readlane first
// (sa pinned to SGPRs via asm "+s"), THEN all 48 fmas (P pinned to VGPRs
// via asm "+v" so no v_accvgpr_read per use). Only the first fma is within
// hazard distance of an SGPR write.
// ---------------------------------------------------------------------------
__global__ __launch_bounds__(64) void crf_scan(
    const float* __restrict__ E, const int* __restrict__ tags,
    const int* __restrict__ lens, const float* __restrict__ begin,
    const float* __restrict__ trans, const float* __restrict__ endt,
    const int* __restrict__ bc, const int* __restrict__ ec,
    const int* __restrict__ tc, float* __restrict__ out) {
  const int s = blockIdx.x;
  const int pass = s & 1;  // 0 = unconstrained fwd, 1 = constrained partial
  const int b = s >> 1;
  const int lane = threadIdx.x;
  const bool act = lane < L_;
  const int len = lens[b];  // in [512, 1024]
  const int stride = B_ * L_;
  const int base = b * L_ + (act ? lane : 0);  // clamped for lanes 48..63

  // Transition row; 0 for inactive lanes and constrained entries
  float P[L_];
#pragma unroll
  for (int k = 0; k < L_; k++) P[k] = 0.f;
  if (act) {
#pragma unroll
    for (int k = 0; k < L_; k++) {
      float p = __expf(trans[lane * L_ + k]);
      if (pass && tc[lane * L_ + k]) p = 0.f;
      P[k] = p;
    }
  }
#pragma unroll
  for (int k = 0; k < L_; k++) asm volatile("" : "+v"(P[k]));  // pin to VGPR

  // init state: a0 = E[0]*exp(begin), masked for pass 1
  float a = 0.f;
  if (act) {
    a = E[base] * __expf(begin[lane]);
    if (pass && (bc[lane] || tags[base])) a = 0.f;
  }
  float logacc = 0.f;

  // pre-masked emission load: 0 where the tag mask disallows (pass 1 only)
  auto ldE = [&](int tt) -> float {
    float v = E[tt * stride + base];
    if (pass && tags[tt * stride + base]) v = 0.f;
    return v;
  };

  auto step = [&](float ev, bool rescale) {
    // phase 1: broadcast whole state into SGPRs (order-pinned)
    const int ai = __float_as_int(a);
    int sa[L_];
#pragma unroll
    for (int k = 0; k < L_; k++) {
      sa[k] = __builtin_amdgcn_readlane(ai, k);
      asm volatile("" : "+s"(sa[k]));  // keep in SGPR, no v_mov round trip
    }
    __builtin_amdgcn_sched_barrier(0);  // no interleave: hazards amortized
    // phase 2: matvec, 4 independent chains (SGPR src0 + VGPR src1)
    float s0 = 0.f, s1 = 0.f, s2 = 0.f, s3 = 0.f;
#pragma unroll
    for (int k = 0; k < L_; k += 4) {
      s0 = fmaf(__int_as_float(sa[k + 0]), P[k + 0], s0);
      s1 = fmaf(__int_as_float(sa[k + 1]), P[k + 1], s1);
      s2 = fmaf(__int_as_float(sa[k + 2]), P[k + 2], s2);
      s3 = fmaf(__int_as_float(sa[k + 3]), P[k + 3], s3);
    }
    __builtin_amdgcn_sched_barrier(0);
    float u = ((s0 + s1) + (s2 + s3)) * ev;
    if (rescale) {
      float m = u;
#pragma unroll
      for (int off = 32; off; off >>= 1) m = fmaxf(m, __shfl_xor(m, off, 64));
      m = fmaxf(m, 1e-30f);
      u = u * __builtin_amdgcn_rcpf(m);  // log(m) compensates; eps ~2^-22
      logacc += __logf(m);
    }
    a = u;
  };

  // preload emissions for t = 1..8 (len >= 512 so always valid)
  float e8[8];
#pragma unroll
  for (int i = 0; i < 8; i++) e8[i] = ldE(1 + i);

  int t = 1;  // t stays == 1 (mod 8); rescale lands at unrolled i == 7
  for (; t + 8 <= len; t += 8) {
    float p8[8];
#pragma unroll
    for (int i = 0; i < 8; i++) {
      int tt = t + 8 + i;
      tt = (tt < len) ? tt : (len - 1);
      p8[i] = ldE(tt);
    }
#pragma unroll
    for (int i = 0; i < 8; i++) step(e8[i], i == 7);
#pragma unroll
    for (int i = 0; i < 8; i++) e8[i] = p8[i];
  }
  // tail: at most 7 steps, e8 already holds times t..t+7 (clamped)
#pragma unroll
  for (int i = 0; i < 8; i++) {
    if (t + i < len) step(e8[i], false);
  }

  // readout: logZ = logacc + log(sum_j a[j]*exp(end[j]))
  float z = 0.f;
  if (act) {
    float ez = __expf(endt[lane]);
    if (pass && ec[lane]) ez = 0.f;
    z = a * ez;
  }
#pragma unroll
  for (int off = 32; off; off >>= 1) z += __shfl_xor(z, off, 64);
  const float logZ = logacc + __logf(z);
  if (lane == 0) atomicAdd(out + b, pass ? -logZ : logZ);
}

// ---------------------------------------------------------------------------
extern "C" void kernel_launch(void* const* d_in, const int* in_sizes, int n_in,
                              void* d_out, int out_size, void* d_ws,
                              size_t ws_size, hipStream_t stream) {
  (void)in_sizes; (void)n_in; (void)out_size; (void)ws_size;
  const float* feats = (const float*)d_in[0];
  const int* tags = (const int*)d_in[1];
  const int* lens = (const int*)d_in[2];
  const float* W = (const float*)d_in[3];
  const float* bias = (const float*)d_in[4];
  const float* begin = (const float*)d_in[5];
  const float* trans = (const float*)d_in[6];
  const float* endt = (const float*)d_in[7];
  const int* bc = (const int*)d_in[8];
  const int* ec = (const int*)d_in[9];
  const int* tc = (const int*)d_in[10];

  float* E = (float*)d_ws;  // T*B*L floats = 6 MB scratch, exp(emissions)
  float* out = (float*)d_out;

  hipMemsetAsync(d_out, 0, B_ * sizeof(float), stream);

  emis_gemm<<<dim3(TB_ / 128), dim3(256), 0, stream>>>(feats, W, bias, E);
  crf_scan<<<dim3(2 * B_), dim3(64), 0, stream>>>(E, tags, lens, begin, trans,
                                                  endt, bc, ec, tc, out);
}

// Round 7
// 797.186 us; speedup vs baseline: 1.0510x; 1.0108x over previous
//
#include <hip/hip_runtime.h>

// Problem constants (from reference): T=1024, B=32, D=768, L=48
#define T_ 1024
#define B_ 32
#define D_ 768
#define L_ 48
#define TB_ (T_ * B_)   // 32768 rows of the emissions GEMM

typedef float v2f __attribute__((ext_vector_type(2)));

// ---------------------------------------------------------------------------
// Kernel A: E = exp(feats @ W + b)  — UNCHANGED (control). Model says ~20 us,
// wall-clock arithmetic says ~190 us; once crf_scan drops below it, this
// kernel tops the top-5 table and we finally get its counters.
// ---------------------------------------------------------------------------
__global__ __launch_bounds__(256, 1) void emis_gemm(
    const float* __restrict__ feats, const float* __restrict__ W,
    const float* __restrict__ bias, float* __restrict__ E) {
  __shared__ float fbuf[2][128 * 64];  // row-major, 16 chunks of 16B per row
  __shared__ float wbuf[2][48 * 68];   // wbuf[j][ko], padded
  const int tid = threadIdx.x;
  const int wv = tid >> 6;   // wave id 0..3
  const int lane = tid & 63;
  const int cg = tid & 7;    // col group -> cols c0..c0+5
  const int rg = tid >> 3;   // row group 0..31 -> rows rg+32i
  const int c0 = cg * 6;
  const int rowbase = blockIdx.x * 128;
  const int r7 = rg & 7;

  float acc[4][6];
#pragma unroll
  for (int i = 0; i < 4; i++)
#pragma unroll
    for (int c = 0; c < 6; c++) acc[i][c] = 0.f;

  float wreg[12];

  auto stage_feats = [&](int kc, int bufi) {
#pragma unroll
    for (int inst = 0; inst < 8; inst++) {
      const int rowstart = wv * 32 + inst * 4;
      const int r = rowstart + (lane >> 4);
      const int slot = lane & 15;
      const int gch = slot ^ (r & 7);
      const float* g = feats + (size_t)(rowbase + r) * D_ + kc + gch * 4;
      float* l = &fbuf[bufi][rowstart * 64];  // wave-uniform base
      __builtin_amdgcn_global_load_lds(
          (const __attribute__((address_space(1))) uint32_t*)g,
          (__attribute__((address_space(3))) uint32_t*)l, 16, 0, 0);
    }
  };
  auto load_w = [&](int kc) {
#pragma unroll
    for (int i = 0; i < 12; i++) {
      const int idx = tid + i * 256;  // 0..3071
      const int ko = idx / 48;
      const int j = idx - ko * 48;
      wreg[i] = W[(kc + ko) * L_ + j];
    }
  };
  auto store_w = [&](int bufi) {
#pragma unroll
    for (int i = 0; i < 12; i++) {
      const int idx = tid + i * 256;
      const int ko = idx / 48;
      const int j = idx - ko * 48;
      wbuf[bufi][j * 68 + ko] = wreg[i];  // transposed: wbuf[j][ko]
    }
  };

  stage_feats(0, 0);
  load_w(0);
  store_w(0);
  __syncthreads();  // drains feats chunk0 (vmcnt) + W writes (lgkm)

  for (int c = 0; c < 12; c++) {
    const int cur = c & 1, nxt = cur ^ 1;
    if (c + 1 < 12) {
      stage_feats((c + 1) * 64, nxt);  // async; lands during compute
      load_w((c + 1) * 64);            // VGPR loads; land during compute
    }
#pragma unroll 4
    for (int k4 = 0; k4 < 16; k4++) {
      float4 fv[4];
      float4 wv4[6];
      const int sch = (k4 ^ r7) << 2;  // swizzled chunk offset (floats)
#pragma unroll
      for (int i = 0; i < 4; i++)
        fv[i] = *(const float4*)(&fbuf[cur][(rg + 32 * i) * 64 + sch]);
#pragma unroll
      for (int cc = 0; cc < 6; cc++)
        wv4[cc] = *(const float4*)(&wbuf[cur][(c0 + cc) * 68 + k4 * 4]);
#pragma unroll
      for (int i = 0; i < 4; i++) {
#pragma unroll
        for (int cc = 0; cc < 6; cc++) {
          acc[i][cc] = fmaf(fv[i].x, wv4[cc].x, acc[i][cc]);
          acc[i][cc] = fmaf(fv[i].y, wv4[cc].y, acc[i][cc]);
          acc[i][cc] = fmaf(fv[i].z, wv4[cc].z, acc[i][cc]);
          acc[i][cc] = fmaf(fv[i].w, wv4[cc].w, acc[i][cc]);
        }
      }
    }
    if (c + 1 < 12) store_w(nxt);  // W loads landed during compute
    __syncthreads();               // all waves done with [cur]; [nxt] staged
  }

#pragma unroll
  for (int i = 0; i < 4; i++) {
    float* dst = E + (size_t)(rowbase + rg + 32 * i) * L_ + c0;
#pragma unroll
    for (int c = 0; c < 6; c += 2) {
      float2 v;
      v.x = __expf(acc[i][c + 0] + bias[c0 + c + 0]);
      v.y = __expf(acc[i][c + 1] + bias[c0 + c + 1]);
      *(float2*)(dst + c) = v;
    }
  }
}

// ---------------------------------------------------------------------------
// Kernel B: CRF forward scans, scaled probability space.
// 64 blocks x 1 wave. R7: NO readlane (quarter-rate, R2-R6 evidence: 568
// cyc/step invariant under scheduling = unit-throughput limit). Broadcast
// via single-wave LDS round trip instead: ds_write_b32 state, compiler
// lgkmcnt, 12 broadcast ds_read_b128 (same-addr = conflict-free), then
// 24 packed v_pk_fma_f32 (v2f + elementwise_fma). No s_barrier needed:
// DS ops within one wave are ordered, lgkmcnt covers the write->read dep.
// ---------------------------------------------------------------------------
__global__ __launch_bounds__(64) void crf_scan(
    const float* __restrict__ E, const int* __restrict__ tags,
    const int* __restrict__ lens, const float* __restrict__ begin,
    const float* __restrict__ trans, const float* __restrict__ endt,
    const int* __restrict__ bc, const int* __restrict__ ec,
    const int* __restrict__ tc, float* __restrict__ out) {
  const int s = blockIdx.x;
  const int pass = s & 1;  // 0 = unconstrained fwd, 1 = constrained partial
  const int b = s >> 1;
  const int lane = threadIdx.x;
  const bool act = lane < L_;
  const int len = lens[b];  // in [512, 1024]
  const int stride = B_ * L_;
  const int base = b * L_ + (act ? lane : 0);  // clamped for lanes 48..63

  __shared__ float st[64];  // state broadcast line (only [0,48) read)

  // Transition row as 24 float2 pairs; 0 for inactive/constrained entries
  v2f Pv[L_ / 2];
#pragma unroll
  for (int q = 0; q < L_ / 2; q++) Pv[q] = (v2f){0.f, 0.f};
  if (act) {
#pragma unroll
    for (int q = 0; q < L_ / 2; q++) {
      float p0 = __expf(trans[lane * L_ + 2 * q + 0]);
      float p1 = __expf(trans[lane * L_ + 2 * q + 1]);
      if (pass && tc[lane * L_ + 2 * q + 0]) p0 = 0.f;
      if (pass && tc[lane * L_ + 2 * q + 1]) p1 = 0.f;
      Pv[q] = (v2f){p0, p1};
    }
  }

  // init state: a0 = E[0]*exp(begin), masked for pass 1 (inactive lanes: 0)
  float a = 0.f;
  if (act) {
    a = E[base] * __expf(begin[lane]);
    if (pass && (bc[lane] || tags[base])) a = 0.f;
  }
  float logacc = 0.f;

  // pre-masked emission load: 0 where the tag mask disallows (pass 1 only)
  auto ldE = [&](int tt) -> float {
    float v = E[tt * stride + base];
    if (pass && tags[tt * stride + base]) v = 0.f;
    return v;
  };

  auto step = [&](float ev, bool rescale) {
    st[lane] = a;  // ds_write_b32; in-order vs following reads (one wave)
    v2f s01 = (v2f){0.f, 0.f};
    v2f s23 = (v2f){0.f, 0.f};
    const float4* c4 = (const float4*)st;
#pragma unroll
    for (int q = 0; q < 12; q++) {
      const float4 v = c4[q];  // broadcast ds_read_b128
      s01 = __builtin_elementwise_fma((v2f){v.x, v.y}, Pv[2 * q + 0], s01);
      s23 = __builtin_elementwise_fma((v2f){v.z, v.w}, Pv[2 * q + 1], s23);
    }
    float u = ((s01.x + s01.y) + (s23.x + s23.y)) * ev;
    if (rescale) {
      float m = u;
#pragma unroll
      for (int off = 32; off; off >>= 1) m = fmaxf(m, __shfl_xor(m, off, 64));
      m = fmaxf(m, 1e-30f);
      u = u * __builtin_amdgcn_rcpf(m);  // log(m) compensates; eps ~2^-22
      logacc += __logf(m);
    }
    a = u;
  };

  // preload emissions for t = 1..8 (len >= 512 so always valid)
  float e8[8];
#pragma unroll
  for (int i = 0; i < 8; i++) e8[i] = ldE(1 + i);

  int t = 1;  // t stays == 1 (mod 8); rescale lands at unrolled i == 7
  for (; t + 8 <= len; t += 8) {
    float p8[8];
#pragma unroll
    for (int i = 0; i < 8; i++) {
      int tt = t + 8 + i;
      tt = (tt < len) ? tt : (len - 1);
      p8[i] = ldE(tt);
    }
#pragma unroll
    for (int i = 0; i < 8; i++) step(e8[i], i == 7);
#pragma unroll
    for (int i = 0; i < 8; i++) e8[i] = p8[i];
  }
  // tail: at most 7 steps, e8 already holds times t..t+7 (clamped)
#pragma unroll
  for (int i = 0; i < 8; i++) {
    if (t + i < len) step(e8[i], false);
  }

  // readout: logZ = logacc + log(sum_j a[j]*exp(end[j]))
  float z = 0.f;
  if (act) {
    float ez = __expf(endt[lane]);
    if (pass && ec[lane]) ez = 0.f;
    z = a * ez;
  }
#pragma unroll
  for (int off = 32; off; off >>= 1) z += __shfl_xor(z, off, 64);
  const float logZ = logacc + __logf(z);
  if (lane == 0) atomicAdd(out + b, pass ? -logZ : logZ);
}

// ---------------------------------------------------------------------------
extern "C" void kernel_launch(void* const* d_in, const int* in_sizes, int n_in,
                              void* d_out, int out_size, void* d_ws,
                              size_t ws_size, hipStream_t stream) {
  (void)in_sizes; (void)n_in; (void)out_size; (void)ws_size;
  const float* feats = (const float*)d_in[0];
  const int* tags = (const int*)d_in[1];
  const int* lens = (const int*)d_in[2];
  const float* W = (const float*)d_in[3];
  const float* bias = (const float*)d_in[4];
  const float* begin = (const float*)d_in[5];
  const float* trans = (const float*)d_in[6];
  const float* endt = (const float*)d_in[7];
  const int* bc = (const int*)d_in[8];
  const int* ec = (const int*)d_in[9];
  const int* tc = (const int*)d_in[10];

  float* E = (float*)d_ws;  // T*B*L floats = 6 MB scratch, exp(emissions)
  float* out = (float*)d_out;

  hipMemsetAsync(d_out, 0, B_ * sizeof(float), stream);

  emis_gemm<<<dim3(TB_ / 128), dim3(256), 0, stream>>>(feats, W, bias, E);
  crf_scan<<<dim3(2 * B_), dim3(64), 0, stream>>>(E, tags, lens, begin, trans,
                                                  endt, bc, ec, tc, out);
}

// Round 8
// 789.365 us; speedup vs baseline: 1.0614x; 1.0099x over previous
//
#include <hip/hip_runtime.h>

// Problem constants (from reference): T=1024, B=32, D=768, L=48
#define T_ 1024
#define B_ 32
#define D_ 768
#define L_ 48
#define TB_ (T_ * B_)   // 32768 rows of the emissions GEMM

typedef float v2f __attribute__((ext_vector_type(2)));

// ---------------------------------------------------------------------------
// Kernel A: E = exp(feats @ W + b)  — UNCHANGED (control). Remainder
// arithmetic says ~190 us; once crf_scan < that, this tops the table.
// ---------------------------------------------------------------------------
__global__ __launch_bounds__(256, 1) void emis_gemm(
    const float* __restrict__ feats, const float* __restrict__ W,
    const float* __restrict__ bias, float* __restrict__ E) {
  __shared__ float fbuf[2][128 * 64];  // row-major, 16 chunks of 16B per row
  __shared__ float wbuf[2][48 * 68];   // wbuf[j][ko], padded
  const int tid = threadIdx.x;
  const int wv = tid >> 6;   // wave id 0..3
  const int lane = tid & 63;
  const int cg = tid & 7;    // col group -> cols c0..c0+5
  const int rg = tid >> 3;   // row group 0..31 -> rows rg+32i
  const int c0 = cg * 6;
  const int rowbase = blockIdx.x * 128;
  const int r7 = rg & 7;

  float acc[4][6];
#pragma unroll
  for (int i = 0; i < 4; i++)
#pragma unroll
    for (int c = 0; c < 6; c++) acc[i][c] = 0.f;

  float wreg[12];

  auto stage_feats = [&](int kc, int bufi) {
#pragma unroll
    for (int inst = 0; inst < 8; inst++) {
      const int rowstart = wv * 32 + inst * 4;
      const int r = rowstart + (lane >> 4);
      const int slot = lane & 15;
      const int gch = slot ^ (r & 7);
      const float* g = feats + (size_t)(rowbase + r) * D_ + kc + gch * 4;
      float* l = &fbuf[bufi][rowstart * 64];  // wave-uniform base
      __builtin_amdgcn_global_load_lds(
          (const __attribute__((address_space(1))) uint32_t*)g,
          (__attribute__((address_space(3))) uint32_t*)l, 16, 0, 0);
    }
  };
  auto load_w = [&](int kc) {
#pragma unroll
    for (int i = 0; i < 12; i++) {
      const int idx = tid + i * 256;  // 0..3071
      const int ko = idx / 48;
      const int j = idx - ko * 48;
      wreg[i] = W[(kc + ko) * L_ + j];
    }
  };
  auto store_w = [&](int bufi) {
#pragma unroll
    for (int i = 0; i < 12; i++) {
      const int idx = tid + i * 256;
      const int ko = idx / 48;
      const int j = idx - ko * 48;
      wbuf[bufi][j * 68 + ko] = wreg[i];  // transposed: wbuf[j][ko]
    }
  };

  stage_feats(0, 0);
  load_w(0);
  store_w(0);
  __syncthreads();  // drains feats chunk0 (vmcnt) + W writes (lgkm)

  for (int c = 0; c < 12; c++) {
    const int cur = c & 1, nxt = cur ^ 1;
    if (c + 1 < 12) {
      stage_feats((c + 1) * 64, nxt);  // async; lands during compute
      load_w((c + 1) * 64);            // VGPR loads; land during compute
    }
#pragma unroll 4
    for (int k4 = 0; k4 < 16; k4++) {
      float4 fv[4];
      float4 wv4[6];
      const int sch = (k4 ^ r7) << 2;  // swizzled chunk offset (floats)
#pragma unroll
      for (int i = 0; i < 4; i++)
        fv[i] = *(const float4*)(&fbuf[cur][(rg + 32 * i) * 64 + sch]);
#pragma unroll
      for (int cc = 0; cc < 6; cc++)
        wv4[cc] = *(const float4*)(&wbuf[cur][(c0 + cc) * 68 + k4 * 4]);
#pragma unroll
      for (int i = 0; i < 4; i++) {
#pragma unroll
        for (int cc = 0; cc < 6; cc++) {
          acc[i][cc] = fmaf(fv[i].x, wv4[cc].x, acc[i][cc]);
          acc[i][cc] = fmaf(fv[i].y, wv4[cc].y, acc[i][cc]);
          acc[i][cc] = fmaf(fv[i].z, wv4[cc].z, acc[i][cc]);
          acc[i][cc] = fmaf(fv[i].w, wv4[cc].w, acc[i][cc]);
        }
      }
    }
    if (c + 1 < 12) store_w(nxt);  // W loads landed during compute
    __syncthreads();               // all waves done with [cur]; [nxt] staged
  }

#pragma unroll
  for (int i = 0; i < 4; i++) {
    float* dst = E + (size_t)(rowbase + rg + 32 * i) * L_ + c0;
#pragma unroll
    for (int c = 0; c < 6; c += 2) {
      float2 v;
      v.x = __expf(acc[i][c + 0] + bias[c0 + c + 0]);
      v.y = __expf(acc[i][c + 1] + bias[c0 + c + 1]);
      *(float2*)(dst + c) = v;
    }
  }
}

// ---------------------------------------------------------------------------
// Kernel B: CRF forward scans, scaled probability space.
// 64 blocks x 1 wave. R8: LDS broadcast with the R7 serialization fixed.
// R7 failed because VGPR cap (48) forced read->use->read->use, exposing
// ~120 cyc latency x12 (1415 cyc/step measured, VALUBusy 0.46%). Fix:
// (a) materialize all 12 ds_read_b128 into a float4 vv[12] register array,
// sched_barrier(0) between load phase and fma phase (no reg-pinning asm);
// (b) __launch_bounds__(64,1) so the allocator can keep vv live (~130 VGPR;
// occupancy irrelevant at 64 blocks / 256 CUs).
// Target ~250-300 cyc/step vs 568 (readlane) / 1415 (R7).
// ---------------------------------------------------------------------------
__global__ __launch_bounds__(64, 1) void crf_scan(
    const float* __restrict__ E, const int* __restrict__ tags,
    const int* __restrict__ lens, const float* __restrict__ begin,
    const float* __restrict__ trans, const float* __restrict__ endt,
    const int* __restrict__ bc, const int* __restrict__ ec,
    const int* __restrict__ tc, float* __restrict__ out) {
  const int s = blockIdx.x;
  const int pass = s & 1;  // 0 = unconstrained fwd, 1 = constrained partial
  const int b = s >> 1;
  const int lane = threadIdx.x;
  const bool act = lane < L_;
  const int len = lens[b];  // in [512, 1024]
  const int stride = B_ * L_;
  const int base = b * L_ + (act ? lane : 0);  // clamped for lanes 48..63

  __shared__ __align__(16) float st[64];  // state broadcast line

  // Transition row as 24 float2 pairs; 0 for inactive/constrained entries
  v2f Pv[L_ / 2];
#pragma unroll
  for (int q = 0; q < L_ / 2; q++) Pv[q] = (v2f){0.f, 0.f};
  if (act) {
#pragma unroll
    for (int q = 0; q < L_ / 2; q++) {
      float p0 = __expf(trans[lane * L_ + 2 * q + 0]);
      float p1 = __expf(trans[lane * L_ + 2 * q + 1]);
      if (pass && tc[lane * L_ + 2 * q + 0]) p0 = 0.f;
      if (pass && tc[lane * L_ + 2 * q + 1]) p1 = 0.f;
      Pv[q] = (v2f){p0, p1};
    }
  }

  // init state: a0 = E[0]*exp(begin), masked for pass 1 (inactive lanes: 0)
  float a = 0.f;
  if (act) {
    a = E[base] * __expf(begin[lane]);
    if (pass && (bc[lane] || tags[base])) a = 0.f;
  }
  float logacc = 0.f;

  // pre-masked emission load: 0 where the tag mask disallows (pass 1 only)
  auto ldE = [&](int tt) -> float {
    float v = E[tt * stride + base];
    if (pass && tags[tt * stride + base]) v = 0.f;
    return v;
  };

  auto step = [&](float ev, bool rescale) {
    st[lane] = a;  // ds_write_b32; ordered vs following reads (single wave)
    const float4* c4 = (const float4*)st;
    float4 vv[12];
    // phase 1: issue ALL broadcast reads (12x ds_read_b128, same-addr)
#pragma unroll
    for (int q = 0; q < 12; q++) vv[q] = c4[q];
    __builtin_amdgcn_sched_barrier(0);  // keep fmas out of the load phase
    // phase 2: packed matvec, 2 independent v2 chains
    v2f s01 = (v2f){0.f, 0.f};
    v2f s23 = (v2f){0.f, 0.f};
#pragma unroll
    for (int q = 0; q < 12; q++) {
      s01 = __builtin_elementwise_fma((v2f){vv[q].x, vv[q].y}, Pv[2 * q + 0], s01);
      s23 = __builtin_elementwise_fma((v2f){vv[q].z, vv[q].w}, Pv[2 * q + 1], s23);
    }
    float u = ((s01.x + s01.y) + (s23.x + s23.y)) * ev;
    if (rescale) {
      float m = u;
#pragma unroll
      for (int off = 32; off; off >>= 1) m = fmaxf(m, __shfl_xor(m, off, 64));
      m = fmaxf(m, 1e-30f);
      u = u * __builtin_amdgcn_rcpf(m);  // log(m) compensates; eps ~2^-22
      logacc += __logf(m);
    }
    a = u;
  };

  // preload emissions for t = 1..8 (len >= 512 so always valid)
  float e8[8];
#pragma unroll
  for (int i = 0; i < 8; i++) e8[i] = ldE(1 + i);

  int t = 1;  // t stays == 1 (mod 8); rescale lands at unrolled i == 7
  for (; t + 8 <= len; t += 8) {
    float p8[8];
#pragma unroll
    for (int i = 0; i < 8; i++) {
      int tt = t + 8 + i;
      tt = (tt < len) ? tt : (len - 1);
      p8[i] = ldE(tt);
    }
#pragma unroll
    for (int i = 0; i < 8; i++) step(e8[i], i == 7);
#pragma unroll
    for (int i = 0; i < 8; i++) e8[i] = p8[i];
  }
  // tail: at most 7 steps, e8 already holds times t..t+7 (clamped)
#pragma unroll
  for (int i = 0; i < 8; i++) {
    if (t + i < len) step(e8[i], false);
  }

  // readout: logZ = logacc + log(sum_j a[j]*exp(end[j]))
  float z = 0.f;
  if (act) {
    float ez = __expf(endt[lane]);
    if (pass && ec[lane]) ez = 0.f;
    z = a * ez;
  }
#pragma unroll
  for (int off = 32; off; off >>= 1) z += __shfl_xor(z, off, 64);
  const float logZ = logacc + __logf(z);
  if (lane == 0) atomicAdd(out + b, pass ? -logZ : logZ);
}

// ---------------------------------------------------------------------------
extern "C" void kernel_launch(void* const* d_in, const int* in_sizes, int n_in,
                              void* d_out, int out_size, void* d_ws,
                              size_t ws_size, hipStream_t stream) {
  (void)in_sizes; (void)n_in; (void)out_size; (void)ws_size;
  const float* feats = (const float*)d_in[0];
  const int* tags = (const int*)d_in[1];
  const int* lens = (const int*)d_in[2];
  const float* W = (const float*)d_in[3];
  const float* bias = (const float*)d_in[4];
  const float* begin = (const float*)d_in[5];
  const float* trans = (const float*)d_in[6];
  const float* endt = (const float*)d_in[7];
  const int* bc = (const int*)d_in[8];
  const int* ec = (const int*)d_in[9];
  const int* tc = (const int*)d_in[10];

  float* E = (float*)d_ws;  // T*B*L floats = 6 MB scratch, exp(emissions)
  float* out = (float*)d_out;

  hipMemsetAsync(d_out, 0, B_ * sizeof(float), stream);

  emis_gemm<<<dim3(TB_ / 128), dim3(256), 0, stream>>>(feats, W, bias, E);
  crf_scan<<<dim3(2 * B_), dim3(64), 0, stream>>>(E, tags, lens, begin, trans,
                                                  endt, bc, ec, tc, out);
}